// Round 1
// baseline (894.716 us; speedup 1.0000x reference)
//
#include <hip/hip_runtime.h>
#include <math.h>

// Problem constants
#define B   32
#define TU  128
#define TM  128
#define TZ  32
#define TENC 288
#define V   10000
#define H   512
#define E   128
#define S   640          // E + H
#define G3  1536         // 3*H
#define NLOG (V + TENC)  // 10288

// Workspace layout (float offsets)
#define WS_Q      0                       // B*H
#define WS_SCORE  (WS_Q + B*H)            // B*TENC
#define WS_CTX    (WS_SCORE + B*TENC)     // B*H
#define WS_GI     (WS_CTX + B*H)          // B*G3
#define WS_GH     (WS_GI + B*G3)          // B*G3
#define WS_ST     (WS_GH + B*G3)          // B*S
#define WS_LOGIT  (WS_ST + B*S)           // B*NLOG
#define WS_PCOPY  (WS_LOGIT + B*NLOG)     // B*TENC
#define WS_TOTAL  (WS_PCOPY + B*TENC)

__device__ __forceinline__ float fast_tanh(float x) {
    // tanh(x) = 1 - 2/(e^{2x}+1); saturates correctly at +-inf
    return 1.f - 2.f / (__expf(2.f * x) + 1.f);
}

__device__ __forceinline__ const float* enc_row(const float* u, const float* m,
                                                const float* pz, int b, int t) {
    if (t < TU) return u + ((size_t)b * TU + t) * H;
    if (t < TU + TM) return m + ((size_t)b * TM + (t - TU)) * H;
    return pz + ((size_t)b * TZ + (t - TU - TM)) * H;
}

// K1: q[b,g] = h0[b]·W_attn[g, :H] + b_attn[g]
__global__ __launch_bounds__(256) void k_q(const float* __restrict__ last_hidden,
                                           const float* __restrict__ W_attn,
                                           const float* __restrict__ b_attn,
                                           float* __restrict__ ws) {
    int b = blockIdx.x, tid = threadIdx.x;
    __shared__ float h0[H];
    for (int i = tid; i < H; i += 256) h0[i] = last_hidden[b * H + i];
    __syncthreads();
    for (int g = tid; g < H; g += 256) {
        const float* w = W_attn + (size_t)g * (2 * H);
        float acc = 0.f;
        for (int k = 0; k < H; k += 4) {
            float4 wv = *(const float4*)(w + k);
            acc += wv.x * h0[k] + wv.y * h0[k + 1] + wv.z * h0[k + 2] + wv.w * h0[k + 3];
        }
        ws[WS_Q + b * H + g] = acc + b_attn[g];
    }
}

// K2: score[b,t] = sum_g tanh(q[b,g] + enc[b,t]·W_attn[g, H:]) * v_attn[g]
// block = (b, 16-row t-tile); 256 threads, each owns 2 g values
__global__ __launch_bounds__(256) void k_attn_score(const float* __restrict__ u_h,
                                                    const float* __restrict__ m_h,
                                                    const float* __restrict__ pz_h,
                                                    const float* __restrict__ W_attn,
                                                    const float* __restrict__ v_attn,
                                                    float* __restrict__ ws) {
    int blk = blockIdx.x;              // 0..575
    int b = blk / 18, t0 = (blk % 18) * 16;
    int tid = threadIdx.x;
    __shared__ float lds[16 * H];      // 32 KB
    __shared__ float red[4][16];
    const float* base = enc_row(u_h, m_h, pz_h, b, t0);  // 16 rows contiguous in-segment
    for (int i = tid * 4; i < 16 * H; i += 256 * 4)
        *(float4*)(lds + i) = *(const float4*)(base + i);
    __syncthreads();

    int g0 = tid, g1 = tid + 256;
    const float* w0p = W_attn + (size_t)g0 * (2 * H) + H;
    const float* w1p = W_attn + (size_t)g1 * (2 * H) + H;
    float acc0[16], acc1[16];
#pragma unroll
    for (int t = 0; t < 16; ++t) { acc0[t] = 0.f; acc1[t] = 0.f; }
    for (int k = 0; k < H; k += 4) {
        float4 w0 = *(const float4*)(w0p + k);
        float4 w1 = *(const float4*)(w1p + k);
#pragma unroll
        for (int t = 0; t < 16; ++t) {
            float4 a = *(const float4*)(lds + t * H + k);
            acc0[t] += w0.x * a.x + w0.y * a.y + w0.z * a.z + w0.w * a.w;
            acc1[t] += w1.x * a.x + w1.y * a.y + w1.z * a.z + w1.w * a.w;
        }
    }
    float q0 = ws[WS_Q + b * H + g0], q1 = ws[WS_Q + b * H + g1];
    float va0 = v_attn[g0], va1 = v_attn[g1];
    int lane = tid & 63, wv = tid >> 6;
#pragma unroll
    for (int t = 0; t < 16; ++t) {
        float v = fast_tanh(acc0[t] + q0) * va0 + fast_tanh(acc1[t] + q1) * va1;
        for (int off = 32; off > 0; off >>= 1) v += __shfl_down(v, off, 64);
        if (lane == 0) red[wv][t] = v;
    }
    __syncthreads();
    if (tid < 16)
        ws[WS_SCORE + b * TENC + t0 + tid] = red[0][tid] + red[1][tid] + red[2][tid] + red[3][tid];
}

// K3: softmax over t (288) and context[b,h] = sum_t w[t]*enc[b,t,h]
// grid (B, 2): each block handles 256 h values
__global__ __launch_bounds__(256) void k_softmax_ctx(const float* __restrict__ u_h,
                                                     const float* __restrict__ m_h,
                                                     const float* __restrict__ pz_h,
                                                     float* __restrict__ ws) {
    int b = blockIdx.x, tid = threadIdx.x;
    __shared__ float wsm[TENC];
    __shared__ float red1[4], red2[4];
    float local = -1e30f;
    for (int t = tid; t < TENC; t += 256) {
        float s = ws[WS_SCORE + b * TENC + t];
        wsm[t] = s;
        local = fmaxf(local, s);
    }
    int lane = tid & 63, wv = tid >> 6;
    for (int off = 32; off > 0; off >>= 1) local = fmaxf(local, __shfl_down(local, off, 64));
    if (lane == 0) red1[wv] = local;
    __syncthreads();
    float mx = fmaxf(fmaxf(red1[0], red1[1]), fmaxf(red1[2], red1[3]));
    float ls = 0.f;
    for (int t = tid; t < TENC; t += 256) {
        float e = __expf(wsm[t] - mx);
        wsm[t] = e;
        ls += e;
    }
    for (int off = 32; off > 0; off >>= 1) ls += __shfl_down(ls, off, 64);
    if (lane == 0) red2[wv] = ls;
    __syncthreads();
    float inv = 1.f / (red2[0] + red2[1] + red2[2] + red2[3]);

    int h = blockIdx.y * 256 + tid;
    float acc = 0.f;
    for (int t = 0; t < TU; ++t) acc += wsm[t] * u_h[((size_t)b * TU + t) * H + h];
    for (int t = 0; t < TM; ++t) acc += wsm[TU + t] * m_h[((size_t)b * TM + t) * H + h];
    for (int t = 0; t < TZ; ++t) acc += wsm[TU + TM + t] * pz_h[((size_t)b * TZ + t) * H + h];
    ws[WS_CTX + b * H + h] = acc * inv;
}

// K4: gi = x@W_ih^T + b_ih, gh = h0@W_hh^T + b_hh.  grid (6 rblk, 8 btile-of-4)
__global__ __launch_bounds__(256) void k_gru_mm(const float* __restrict__ emb,
                                               const float* __restrict__ last_hidden,
                                               const float* __restrict__ W_ih,
                                               const float* __restrict__ W_hh,
                                               const float* __restrict__ b_ih,
                                               const float* __restrict__ b_hh,
                                               float* __restrict__ ws) {
    int r = blockIdx.x * 256 + threadIdx.x;   // 0..1535
    int b0 = blockIdx.y * 4;
    int tid = threadIdx.x;
    __shared__ float x[4][S];
    __shared__ float hh[4][H];
    for (int i = tid; i < 4 * S; i += 256) {
        int bb = i / S, s = i % S;
        x[bb][s] = (s < E) ? emb[(b0 + bb) * E + s] : ws[WS_CTX + (b0 + bb) * H + (s - E)];
    }
    for (int i = tid; i < 4 * H; i += 256) {
        int bb = i / H, h = i % H;
        hh[bb][h] = last_hidden[(b0 + bb) * H + h];
    }
    __syncthreads();
    float ai[4] = {0, 0, 0, 0}, ah[4] = {0, 0, 0, 0};
    const float* wi = W_ih + (size_t)r * S;
    for (int k = 0; k < S; k += 4) {
        float4 w = *(const float4*)(wi + k);
#pragma unroll
        for (int bb = 0; bb < 4; ++bb)
            ai[bb] += w.x * x[bb][k] + w.y * x[bb][k + 1] + w.z * x[bb][k + 2] + w.w * x[bb][k + 3];
    }
    const float* wh = W_hh + (size_t)r * H;
    for (int k = 0; k < H; k += 4) {
        float4 w = *(const float4*)(wh + k);
#pragma unroll
        for (int bb = 0; bb < 4; ++bb)
            ah[bb] += w.x * hh[bb][k] + w.y * hh[bb][k + 1] + w.z * hh[bb][k + 2] + w.w * hh[bb][k + 3];
    }
    float bi = b_ih[r], bh = b_hh[r];
    for (int bb = 0; bb < 4; ++bb) {
        ws[WS_GI + (b0 + bb) * G3 + r] = ai[bb] + bi;
        ws[WS_GH + (b0 + bb) * G3 + r] = ah[bb] + bh;
    }
}

// K5: GRU pointwise; writes h_new to both outputs and st to ws
__global__ __launch_bounds__(256) void k_gru_combine(const float* __restrict__ emb,
                                                     const float* __restrict__ last_hidden,
                                                     float* __restrict__ ws,
                                                     float* __restrict__ out) {
    int i = blockIdx.x * 256 + threadIdx.x;   // 0..16383
    int b = i >> 9, h = i & 511;
    float gi_r = ws[WS_GI + b * G3 + h];
    float gi_z = ws[WS_GI + b * G3 + H + h];
    float gi_n = ws[WS_GI + b * G3 + 2 * H + h];
    float gh_r = ws[WS_GH + b * G3 + h];
    float gh_z = ws[WS_GH + b * G3 + H + h];
    float gh_n = ws[WS_GH + b * G3 + 2 * H + h];
    float rr = 1.f / (1.f + __expf(-(gi_r + gh_r)));
    float zz = 1.f / (1.f + __expf(-(gi_z + gh_z)));
    float nn = fast_tanh(gi_n + rr * gh_n);
    float hp = last_hidden[b * H + h];
    float hn = (1.f - zz) * nn + zz * hp;
    out[V * B + b * H + h] = hn;              // last_hidden_new (1,B,H)
    out[V * B + B * H + b * H + h] = hn;      // gru_out (B,1,H)
    ws[WS_ST + b * S + h] = hn;
    if (h < E) ws[WS_ST + b * S + H + h] = emb[b * E + h];
}

// K6: sc[b,t] = sum_s tanh(enc[b,t]·Wseg[s] + bias[s]) * st[b,s]
__global__ __launch_bounds__(256) void k_copy_score(const float* __restrict__ u_h,
                                                    const float* __restrict__ m_h,
                                                    const float* __restrict__ pz_h,
                                                    const float* __restrict__ W_cpu,
                                                    const float* __restrict__ b_cpu,
                                                    const float* __restrict__ W_cpm,
                                                    const float* __restrict__ b_cpm,
                                                    const float* __restrict__ W_cppz,
                                                    const float* __restrict__ b_cppz,
                                                    float* __restrict__ ws) {
    int blk = blockIdx.x;
    int b = blk / 18, t0 = (blk % 18) * 16;
    int tid = threadIdx.x;
    const float* W;
    const float* bias;
    if (t0 < TU)           { W = W_cpu;  bias = b_cpu; }
    else if (t0 < TU + TM) { W = W_cpm;  bias = b_cpm; }
    else                   { W = W_cppz; bias = b_cppz; }
    __shared__ float lds[16 * H];
    __shared__ float red[4][16];
    const float* base = enc_row(u_h, m_h, pz_h, b, t0);
    for (int i = tid * 4; i < 16 * H; i += 256 * 4)
        *(float4*)(lds + i) = *(const float4*)(base + i);
    __syncthreads();

    int s0 = tid, s1 = tid + 256, s2 = tid + 512;
    bool has2 = (tid < 128);
    const float* w0p = W + (size_t)s0 * H;
    const float* w1p = W + (size_t)s1 * H;
    const float* w2p = W + (size_t)(has2 ? s2 : 0) * H;
    float acc0[16], acc1[16], acc2[16];
#pragma unroll
    for (int t = 0; t < 16; ++t) { acc0[t] = 0.f; acc1[t] = 0.f; acc2[t] = 0.f; }
    for (int k = 0; k < H; k += 4) {
        float4 w0 = *(const float4*)(w0p + k);
        float4 w1 = *(const float4*)(w1p + k);
        float4 w2 = *(const float4*)(w2p + k);
#pragma unroll
        for (int t = 0; t < 16; ++t) {
            float4 a = *(const float4*)(lds + t * H + k);
            acc0[t] += w0.x * a.x + w0.y * a.y + w0.z * a.z + w0.w * a.w;
            acc1[t] += w1.x * a.x + w1.y * a.y + w1.z * a.z + w1.w * a.w;
            acc2[t] += w2.x * a.x + w2.y * a.y + w2.z * a.z + w2.w * a.w;
        }
    }
    float bi0 = bias[s0], bi1 = bias[s1], bi2 = has2 ? bias[s2] : 0.f;
    float st0 = ws[WS_ST + b * S + s0];
    float st1 = ws[WS_ST + b * S + s1];
    float st2 = has2 ? ws[WS_ST + b * S + s2] : 0.f;
    int lane = tid & 63, wv = tid >> 6;
#pragma unroll
    for (int t = 0; t < 16; ++t) {
        float v = fast_tanh(acc0[t] + bi0) * st0 + fast_tanh(acc1[t] + bi1) * st1;
        if (has2) v += fast_tanh(acc2[t] + bi2) * st2;
        for (int off = 32; off > 0; off >>= 1) v += __shfl_down(v, off, 64);
        if (lane == 0) red[wv][t] = v;
    }
    __syncthreads();
    if (tid < 16)
        ws[WS_LOGIT + (size_t)b * NLOG + V + t0 + tid] =
            red[0][tid] + red[1][tid] + red[2][tid] + red[3][tid];
}

// K7: score_g[b,v] = st[b]·W_gen[v] + b_gen[v].  grid (40 vblk, 4 btile-of-8)
__global__ __launch_bounds__(256) void k_score_g(const float* __restrict__ W_gen,
                                                 const float* __restrict__ b_gen,
                                                 float* __restrict__ ws) {
    int v = blockIdx.x * 256 + threadIdx.x;
    int b0 = blockIdx.y * 8;
    __shared__ float st[8][S];
    for (int i = threadIdx.x; i < 8 * S; i += 256)
        st[i / S][i % S] = ws[WS_ST + (b0 + i / S) * S + (i % S)];
    __syncthreads();
    if (v >= V) return;
    float acc[8] = {0, 0, 0, 0, 0, 0, 0, 0};
    const float* w = W_gen + (size_t)v * S;
    for (int k = 0; k < S; k += 4) {
        float4 wv = *(const float4*)(w + k);
#pragma unroll
        for (int bb = 0; bb < 8; ++bb)
            acc[bb] += wv.x * st[bb][k] + wv.y * st[bb][k + 1] + wv.z * st[bb][k + 2] + wv.w * st[bb][k + 3];
    }
    float bg = b_gen[v];
    for (int bb = 0; bb < 8; ++bb)
        ws[WS_LOGIT + (size_t)(b0 + bb) * NLOG + v] = acc[bb] + bg;
}

// K8: per-b softmax over 10288 logits; p_g -> out, copy probs -> ws
__global__ __launch_bounds__(256) void k_softmax_out(float* __restrict__ ws,
                                                     float* __restrict__ out) {
    int b = blockIdx.x, tid = threadIdx.x;
    __shared__ float red1[4], red2[4];
    const float* lg = ws + WS_LOGIT + (size_t)b * NLOG;
    float mx = -1e30f;
    for (int i = tid; i < NLOG; i += 256) mx = fmaxf(mx, lg[i]);
    int lane = tid & 63, wv = tid >> 6;
    for (int off = 32; off > 0; off >>= 1) mx = fmaxf(mx, __shfl_down(mx, off, 64));
    if (lane == 0) red1[wv] = mx;
    __syncthreads();
    mx = fmaxf(fmaxf(red1[0], red1[1]), fmaxf(red1[2], red1[3]));
    float sm = 0.f;
    for (int i = tid; i < NLOG; i += 256) sm += __expf(lg[i] - mx);
    for (int off = 32; off > 0; off >>= 1) sm += __shfl_down(sm, off, 64);
    if (lane == 0) red2[wv] = sm;
    __syncthreads();
    float inv = 1.f / (red2[0] + red2[1] + red2[2] + red2[3]);
    for (int i = tid; i < NLOG; i += 256) {
        float p = __expf(lg[i] - mx) * inv;
        if (i < V) out[b * V + i] = p;
        else ws[WS_PCOPY + b * TENC + (i - V)] = p;
    }
}

// K9: scatter-add p_u/p_m at token indices (exact one-hot einsum)
__global__ void k_scatter(const int* __restrict__ u_in, const int* __restrict__ m_in,
                          const float* __restrict__ ws, float* __restrict__ out) {
    int b = blockIdx.x, t = threadIdx.x;   // 256 threads = TU + TM
    float p = ws[WS_PCOPY + b * TENC + t];
    int idx = (t < TU) ? u_in[b * TU + t] : m_in[b * TM + (t - TU)];
    atomicAdd(&out[(size_t)b * V + idx], p);
}

// K10: out[b,v] += sum_t p_pz[b,t] * pv_z_prob[b,t,v]
__global__ __launch_bounds__(256) void k_pv(const float* __restrict__ pvp,
                                            const float* __restrict__ ws,
                                            float* __restrict__ out) {
    int b = blockIdx.y;
    int v = blockIdx.x * 256 + threadIdx.x;
    __shared__ float p[TZ];
    if (threadIdx.x < TZ) p[threadIdx.x] = ws[WS_PCOPY + b * TENC + TU + TM + threadIdx.x];
    __syncthreads();
    if (v >= V) return;
    float acc = 0.f;
#pragma unroll 4
    for (int t = 0; t < TZ; ++t) acc += p[t] * pvp[((size_t)b * TZ + t) * V + v];
    out[(size_t)b * V + v] += acc;
}

extern "C" void kernel_launch(void* const* d_in, const int* in_sizes, int n_in,
                              void* d_out, int out_size, void* d_ws, size_t ws_size,
                              hipStream_t stream) {
    const int*   u_input   = (const int*)d_in[0];
    const float* u_h       = (const float*)d_in[2];
    const int*   m_input   = (const int*)d_in[3];
    const float* m_h       = (const float*)d_in[5];
    const float* pv_prob   = (const float*)d_in[6];
    const float* pz_h      = (const float*)d_in[7];
    const float* emb       = (const float*)d_in[9];
    const float* last_h    = (const float*)d_in[10];
    const float* W_attn    = (const float*)d_in[11];
    const float* b_attn    = (const float*)d_in[12];
    const float* v_attn    = (const float*)d_in[13];
    const float* W_ih      = (const float*)d_in[14];
    const float* W_hh      = (const float*)d_in[15];
    const float* b_ih      = (const float*)d_in[16];
    const float* b_hh      = (const float*)d_in[17];
    const float* W_gen     = (const float*)d_in[18];
    const float* b_gen     = (const float*)d_in[19];
    const float* W_cpu     = (const float*)d_in[20];
    const float* b_cpu     = (const float*)d_in[21];
    const float* W_cpm     = (const float*)d_in[22];
    const float* b_cpm     = (const float*)d_in[23];
    const float* W_cppz    = (const float*)d_in[24];
    const float* b_cppz    = (const float*)d_in[25];
    float* ws  = (float*)d_ws;
    float* out = (float*)d_out;

    hipLaunchKernelGGL(k_q, dim3(B), dim3(256), 0, stream, last_h, W_attn, b_attn, ws);
    hipLaunchKernelGGL(k_attn_score, dim3(B * 18), dim3(256), 0, stream,
                       u_h, m_h, pz_h, W_attn, v_attn, ws);
    hipLaunchKernelGGL(k_softmax_ctx, dim3(B, 2), dim3(256), 0, stream, u_h, m_h, pz_h, ws);
    hipLaunchKernelGGL(k_gru_mm, dim3(6, 8), dim3(256), 0, stream,
                       emb, last_h, W_ih, W_hh, b_ih, b_hh, ws);
    hipLaunchKernelGGL(k_gru_combine, dim3(64), dim3(256), 0, stream, emb, last_h, ws, out);
    hipLaunchKernelGGL(k_copy_score, dim3(B * 18), dim3(256), 0, stream,
                       u_h, m_h, pz_h, W_cpu, b_cpu, W_cpm, b_cpm, W_cppz, b_cppz, ws);
    hipLaunchKernelGGL(k_score_g, dim3(40, 4), dim3(256), 0, stream, W_gen, b_gen, ws);
    hipLaunchKernelGGL(k_softmax_out, dim3(B), dim3(256), 0, stream, ws, out);
    hipLaunchKernelGGL(k_scatter, dim3(B), dim3(256), 0, stream, u_input, m_input, ws, out);
    hipLaunchKernelGGL(k_pv, dim3(40, B), dim3(256), 0, stream, pv_prob, ws, out);
}

// Round 3
// 600.933 us; speedup vs baseline: 1.4889x; 1.4889x over previous
//
#include <hip/hip_runtime.h>
#include <math.h>

// Problem constants
#define B   32
#define TU  128
#define TM  128
#define TZ  32
#define TENC 288
#define V   10000
#define H   512
#define E   128
#define S   640          // E + H
#define G3  1536         // 3*H
#define NLOG (V + TENC)  // 10288

// Workspace float region (float offsets)
#define WS_Q      0                       // B*H
#define WS_SCORE  (WS_Q + B*H)            // B*TENC
#define WS_CTX    (WS_SCORE + B*TENC)     // B*H
#define WS_GI     (WS_CTX + B*H)          // B*G3
#define WS_GH     (WS_GI + B*G3)          // B*G3
#define WS_ST     (WS_GH + B*G3)          // B*S
#define WS_LOGIT  (WS_ST + B*S)           // B*NLOG
#define WS_PCOPY  (WS_LOGIT + B*NLOG)     // B*TENC
#define WS_F_TOTAL (WS_PCOPY + B*TENC)    // 499200 floats (16B-aligned)

// bf16 (ushort) region, offsets relative to bf base = (ushort*)(ws + WS_F_TOTAL)
#define BF_WA1  0                         // W_attn[:, :H]  as [g][k], 512*512
#define BF_WA2  (BF_WA1 + 512*512)        // W_attn[:, H:]  as [g][k], 512*512
#define BF_WCP  (BF_WA2 + 512*512)        // W_cpu|W_cpm|W_cppz, each 640*512
#define BF_WGEN (BF_WCP + 3*640*512)      // W_gen [v][s], 10000*640

typedef __attribute__((ext_vector_type(8))) short bf16x8_t;
typedef __attribute__((ext_vector_type(4))) float f32x4_t;
typedef __attribute__((ext_vector_type(16))) float f32x16_t;

__device__ __forceinline__ float fast_tanh(float x) {
    return 1.f - 2.f / (__expf(2.f * x) + 1.f);
}

__device__ __forceinline__ unsigned short f2bf(float x) {
    unsigned int u = __float_as_uint(x);
    u += 0x7fffu + ((u >> 16) & 1u);   // RNE
    return (unsigned short)(u >> 16);
}

// 8 consecutive fp32 -> bf16x8 fragment
__device__ __forceinline__ bf16x8_t cvt8(const float* p) {
    float4 a = *(const float4*)(p);
    float4 b = *(const float4*)(p + 4);
    bf16x8_t r;
    r[0] = (short)f2bf(a.x); r[1] = (short)f2bf(a.y);
    r[2] = (short)f2bf(a.z); r[3] = (short)f2bf(a.w);
    r[4] = (short)f2bf(b.x); r[5] = (short)f2bf(b.y);
    r[6] = (short)f2bf(b.z); r[7] = (short)f2bf(b.w);
    return r;
}

__device__ __forceinline__ const float* enc_row(const float* u, const float* m,
                                                const float* pz, int b, int t) {
    if (t < TU) return u + ((size_t)b * TU + t) * H;
    if (t < TU + TM) return m + ((size_t)b * TM + (t - TU)) * H;
    return pz + ((size_t)b * TZ + (t - TU - TM)) * H;
}

// ---------------- K0: weight fp32 -> bf16 conversion (one launch) ----------
#define CVT_WA_END   131072
#define CVT_WCP_END  (CVT_WA_END + 3*81920)     // 376832
#define CVT_TOTAL    (CVT_WCP_END + 1600000)    // 1976832
__global__ __launch_bounds__(256) void k_cvt_w(const float* __restrict__ W_attn,
                                               const float* __restrict__ W_cpu,
                                               const float* __restrict__ W_cpm,
                                               const float* __restrict__ W_cppz,
                                               const float* __restrict__ W_gen,
                                               unsigned short* __restrict__ bf) {
    int idx = blockIdx.x * 256 + threadIdx.x;
    if (idx >= CVT_TOTAL) return;
    const float* src;
    unsigned short* dst;
    if (idx < CVT_WA_END) {
        int half = idx >> 16;            // 65536 units each
        int r = idx & 65535;
        int g = r >> 7;                  // 128 units per row
        int c = (r & 127) * 4;
        src = W_attn + (size_t)g * 1024 + half * 512 + c;
        dst = bf + (half ? BF_WA2 : BF_WA1) + g * 512 + c;
    } else if (idx < CVT_WCP_END) {
        int r = idx - CVT_WA_END;
        int seg = r / 81920, q = r % 81920;
        const float* s0 = (seg == 0) ? W_cpu : (seg == 1) ? W_cpm : W_cppz;
        src = s0 + (size_t)q * 4;
        dst = bf + BF_WCP + seg * 327680 + q * 4;
    } else {
        int r = idx - CVT_WCP_END;
        src = W_gen + (size_t)r * 4;
        dst = bf + BF_WGEN + (size_t)r * 4;
    }
    float4 v = *(const float4*)src;
    ushort4 o;
    o.x = f2bf(v.x); o.y = f2bf(v.y); o.z = f2bf(v.z); o.w = f2bf(v.w);
    *(ushort4*)dst = o;
}

// ---------------- K1: q[b,g] = h0[b]·W_attn[g,:H] + b_attn[g]  (MFMA 32x32x16)
__global__ __launch_bounds__(256) void k_q_mfma(const float* __restrict__ last_h,
                                                const unsigned short* __restrict__ bf,
                                                const float* __restrict__ b_attn,
                                                float* __restrict__ ws) {
    int tid = threadIdx.x, wave = tid >> 6, lane = tid & 63;
    int m = lane & 31, khalf = lane >> 5;
    int n0 = blockIdx.x * 128 + wave * 32;
    const float* aptr = last_h + (size_t)m * H + khalf * 8;
    const unsigned short* bptr = bf + BF_WA1 + (size_t)(n0 + (lane & 31)) * 512 + khalf * 8;
    f32x16_t acc = {};
    for (int k0 = 0; k0 < 512; k0 += 16) {
        bf16x8_t a = cvt8(aptr + k0);
        bf16x8_t bb = *(const bf16x8_t*)(bptr + k0);
        acc = __builtin_amdgcn_mfma_f32_32x32x16_bf16(a, bb, acc, 0, 0, 0);
    }
    int n = n0 + (lane & 31);
    float bg = b_attn[n];
#pragma unroll
    for (int r = 0; r < 16; ++r) {
        int row = (r & 3) + 8 * (r >> 2) + 4 * khalf;   // b index
        ws[WS_Q + row * H + n] = acc[r] + bg;
    }
}

// ---------------- K2: attn scores via MFMA 16x16x32 ------------------------
// block = (b, 16-row t-tile); 4 waves x 8 g-tiles of 16 = 512 g
// K=32 per MFMA: lane fragment k = quad*8+j spans the full 32-tile.
__global__ __launch_bounds__(256) void k_attn_mfma(const float* __restrict__ u_h,
                                                   const float* __restrict__ m_h,
                                                   const float* __restrict__ pz_h,
                                                   const unsigned short* __restrict__ bf,
                                                   const float* __restrict__ v_attn,
                                                   float* __restrict__ ws) {
    int blk = blockIdx.x;
    int b = blk / 18, t0 = (blk % 18) * 16;
    int tid = threadIdx.x, wave = tid >> 6, lane = tid & 63;
    int n16 = lane & 15, quad = lane >> 4;
    const float* abase = enc_row(u_h, m_h, pz_h, b, t0) + (size_t)n16 * H + quad * 8;
    const unsigned short* wbase = bf + BF_WA2 + (size_t)quad * 8;
    f32x4_t acc[8];
#pragma unroll
    for (int j = 0; j < 8; ++j) acc[j] = (f32x4_t){0.f, 0.f, 0.f, 0.f};
    for (int k0 = 0; k0 < 512; k0 += 32) {
        bf16x8_t a = cvt8(abase + k0);
#pragma unroll
        for (int j = 0; j < 8; ++j) {
            int g0 = (wave * 8 + j) * 16;
            bf16x8_t bb = *(const bf16x8_t*)(wbase + (size_t)(g0 + n16) * 512 + k0);
            acc[j] = __builtin_amdgcn_mfma_f32_16x16x32_bf16(a, bb, acc[j], 0, 0, 0);
        }
    }
    float sval[4] = {0.f, 0.f, 0.f, 0.f};
#pragma unroll
    for (int j = 0; j < 8; ++j) {
        int g = (wave * 8 + j) * 16 + n16;
        float q = ws[WS_Q + b * H + g];
        float va = v_attn[g];
#pragma unroll
        for (int r = 0; r < 4; ++r) sval[r] += fast_tanh(acc[j][r] + q) * va;
    }
#pragma unroll
    for (int r = 0; r < 4; ++r)
        for (int off = 8; off > 0; off >>= 1) sval[r] += __shfl_down(sval[r], off, 64);
    __shared__ float red[4][16];
    if (n16 == 0)
#pragma unroll
        for (int r = 0; r < 4; ++r) red[wave][quad * 4 + r] = sval[r];
    __syncthreads();
    if (tid < 16)
        ws[WS_SCORE + b * TENC + t0 + tid] =
            red[0][tid] + red[1][tid] + red[2][tid] + red[3][tid];
}

// ---------------- K3: softmax over t and context ---------------------------
__global__ __launch_bounds__(256) void k_softmax_ctx(const float* __restrict__ u_h,
                                                     const float* __restrict__ m_h,
                                                     const float* __restrict__ pz_h,
                                                     float* __restrict__ ws) {
    int b = blockIdx.x, tid = threadIdx.x;
    __shared__ float wsm[TENC];
    __shared__ float red1[4], red2[4];
    float local = -1e30f;
    for (int t = tid; t < TENC; t += 256) {
        float s = ws[WS_SCORE + b * TENC + t];
        wsm[t] = s;
        local = fmaxf(local, s);
    }
    int lane = tid & 63, wv = tid >> 6;
    for (int off = 32; off > 0; off >>= 1) local = fmaxf(local, __shfl_down(local, off, 64));
    if (lane == 0) red1[wv] = local;
    __syncthreads();
    float mx = fmaxf(fmaxf(red1[0], red1[1]), fmaxf(red1[2], red1[3]));
    float ls = 0.f;
    for (int t = tid; t < TENC; t += 256) {
        float e = __expf(wsm[t] - mx);
        wsm[t] = e;
        ls += e;
    }
    for (int off = 32; off > 0; off >>= 1) ls += __shfl_down(ls, off, 64);
    if (lane == 0) red2[wv] = ls;
    __syncthreads();
    float inv = 1.f / (red2[0] + red2[1] + red2[2] + red2[3]);

    int h = blockIdx.y * 256 + tid;
    float acc = 0.f;
    for (int t = 0; t < TU; ++t) acc += wsm[t] * u_h[((size_t)b * TU + t) * H + h];
    for (int t = 0; t < TM; ++t) acc += wsm[TU + t] * m_h[((size_t)b * TM + t) * H + h];
    for (int t = 0; t < TZ; ++t) acc += wsm[TU + TM + t] * pz_h[((size_t)b * TZ + t) * H + h];
    ws[WS_CTX + b * H + h] = acc * inv;
}

// ---------------- K4: GRU input/hidden GEMMs (fp32) ------------------------
__global__ __launch_bounds__(256) void k_gru_mm(const float* __restrict__ emb,
                                               const float* __restrict__ last_hidden,
                                               const float* __restrict__ W_ih,
                                               const float* __restrict__ W_hh,
                                               const float* __restrict__ b_ih,
                                               const float* __restrict__ b_hh,
                                               float* __restrict__ ws) {
    int r = blockIdx.x * 256 + threadIdx.x;
    int b0 = blockIdx.y * 4;
    int tid = threadIdx.x;
    __shared__ float x[4][S];
    __shared__ float hh[4][H];
    for (int i = tid; i < 4 * S; i += 256) {
        int bb = i / S, s = i % S;
        x[bb][s] = (s < E) ? emb[(b0 + bb) * E + s] : ws[WS_CTX + (b0 + bb) * H + (s - E)];
    }
    for (int i = tid; i < 4 * H; i += 256) {
        int bb = i / H, h = i % H;
        hh[bb][h] = last_hidden[(b0 + bb) * H + h];
    }
    __syncthreads();
    float ai[4] = {0, 0, 0, 0}, ah[4] = {0, 0, 0, 0};
    const float* wi = W_ih + (size_t)r * S;
    for (int k = 0; k < S; k += 4) {
        float4 w = *(const float4*)(wi + k);
#pragma unroll
        for (int bb = 0; bb < 4; ++bb)
            ai[bb] += w.x * x[bb][k] + w.y * x[bb][k + 1] + w.z * x[bb][k + 2] + w.w * x[bb][k + 3];
    }
    const float* wh = W_hh + (size_t)r * H;
    for (int k = 0; k < H; k += 4) {
        float4 w = *(const float4*)(wh + k);
#pragma unroll
        for (int bb = 0; bb < 4; ++bb)
            ah[bb] += w.x * hh[bb][k] + w.y * hh[bb][k + 1] + w.z * hh[bb][k + 2] + w.w * hh[bb][k + 3];
    }
    float bi = b_ih[r], bh = b_hh[r];
    for (int bb = 0; bb < 4; ++bb) {
        ws[WS_GI + (b0 + bb) * G3 + r] = ai[bb] + bi;
        ws[WS_GH + (b0 + bb) * G3 + r] = ah[bb] + bh;
    }
}

// ---------------- K5: GRU pointwise ---------------------------------------
__global__ __launch_bounds__(256) void k_gru_combine(const float* __restrict__ emb,
                                                     const float* __restrict__ last_hidden,
                                                     float* __restrict__ ws,
                                                     float* __restrict__ out) {
    int i = blockIdx.x * 256 + threadIdx.x;
    int b = i >> 9, h = i & 511;
    float gi_r = ws[WS_GI + b * G3 + h];
    float gi_z = ws[WS_GI + b * G3 + H + h];
    float gi_n = ws[WS_GI + b * G3 + 2 * H + h];
    float gh_r = ws[WS_GH + b * G3 + h];
    float gh_z = ws[WS_GH + b * G3 + H + h];
    float gh_n = ws[WS_GH + b * G3 + 2 * H + h];
    float rr = 1.f / (1.f + __expf(-(gi_r + gh_r)));
    float zz = 1.f / (1.f + __expf(-(gi_z + gh_z)));
    float nn = fast_tanh(gi_n + rr * gh_n);
    float hp = last_hidden[b * H + h];
    float hn = (1.f - zz) * nn + zz * hp;
    out[V * B + b * H + h] = hn;
    out[V * B + B * H + b * H + h] = hn;
    ws[WS_ST + b * S + h] = hn;
    if (h < E) ws[WS_ST + b * S + H + h] = emb[b * E + h];
}

// ---------------- K6: copy scores via MFMA 16x16x32 ------------------------
// block = (b, 16-row t-tile); 4 waves x 10 s-tiles of 16 = 640 s
__global__ __launch_bounds__(256) void k_copy_mfma(const float* __restrict__ u_h,
                                                   const float* __restrict__ m_h,
                                                   const float* __restrict__ pz_h,
                                                   const unsigned short* __restrict__ bf,
                                                   const float* __restrict__ b_cpu,
                                                   const float* __restrict__ b_cpm,
                                                   const float* __restrict__ b_cppz,
                                                   float* __restrict__ ws) {
    int blk = blockIdx.x;
    int b = blk / 18, t0 = (blk % 18) * 16;
    int tid = threadIdx.x, wave = tid >> 6, lane = tid & 63;
    int n16 = lane & 15, quad = lane >> 4;
    int seg = (t0 < TU) ? 0 : (t0 < TU + TM) ? 1 : 2;
    const float* bias = (seg == 0) ? b_cpu : (seg == 1) ? b_cpm : b_cppz;
    const float* abase = enc_row(u_h, m_h, pz_h, b, t0) + (size_t)n16 * H + quad * 8;
    const unsigned short* wbase = bf + BF_WCP + (size_t)seg * 327680 + (size_t)quad * 8;
    f32x4_t acc[10];
#pragma unroll
    for (int j = 0; j < 10; ++j) acc[j] = (f32x4_t){0.f, 0.f, 0.f, 0.f};
    for (int k0 = 0; k0 < 512; k0 += 32) {
        bf16x8_t a = cvt8(abase + k0);
#pragma unroll
        for (int j = 0; j < 10; ++j) {
            int s0 = (wave * 10 + j) * 16;
            bf16x8_t bb = *(const bf16x8_t*)(wbase + (size_t)(s0 + n16) * 512 + k0);
            acc[j] = __builtin_amdgcn_mfma_f32_16x16x32_bf16(a, bb, acc[j], 0, 0, 0);
        }
    }
    float sval[4] = {0.f, 0.f, 0.f, 0.f};
#pragma unroll
    for (int j = 0; j < 10; ++j) {
        int s = (wave * 10 + j) * 16 + n16;
        float bi = bias[s];
        float st = ws[WS_ST + b * S + s];
#pragma unroll
        for (int r = 0; r < 4; ++r) sval[r] += fast_tanh(acc[j][r] + bi) * st;
    }
#pragma unroll
    for (int r = 0; r < 4; ++r)
        for (int off = 8; off > 0; off >>= 1) sval[r] += __shfl_down(sval[r], off, 64);
    __shared__ float red[4][16];
    if (n16 == 0)
#pragma unroll
        for (int r = 0; r < 4; ++r) red[wave][quad * 4 + r] = sval[r];
    __syncthreads();
    if (tid < 16)
        ws[WS_LOGIT + (size_t)b * NLOG + V + t0 + tid] =
            red[0][tid] + red[1][tid] + red[2][tid] + red[3][tid];
}

// ---------------- K7: score_g via MFMA 32x32x16 ----------------------------
__global__ __launch_bounds__(256) void k_score_g_mfma(const unsigned short* __restrict__ bf,
                                                      const float* __restrict__ b_gen,
                                                      float* __restrict__ ws) {
    int tid = threadIdx.x, wave = tid >> 6, lane = tid & 63;
    int m = lane & 31, khalf = lane >> 5;
    int n0 = blockIdx.x * 128 + wave * 32;
    int n = n0 + (lane & 31);
    int nr = (n < V) ? n : (V - 1);
    const float* aptr = ws + WS_ST + (size_t)m * S + khalf * 8;
    const unsigned short* bptr = bf + BF_WGEN + (size_t)nr * 640 + khalf * 8;
    f32x16_t acc = {};
    for (int k0 = 0; k0 < 640; k0 += 16) {
        bf16x8_t a = cvt8(aptr + k0);
        bf16x8_t bb = *(const bf16x8_t*)(bptr + k0);
        acc = __builtin_amdgcn_mfma_f32_32x32x16_bf16(a, bb, acc, 0, 0, 0);
    }
    if (n >= V) return;
    float bg = b_gen[n];
#pragma unroll
    for (int r = 0; r < 16; ++r) {
        int row = (r & 3) + 8 * (r >> 2) + 4 * khalf;   // b index
        ws[WS_LOGIT + (size_t)row * NLOG + n] = acc[r] + bg;
    }
}

// ---------------- K8: final softmax ---------------------------------------
__global__ __launch_bounds__(256) void k_softmax_out(float* __restrict__ ws,
                                                     float* __restrict__ out) {
    int b = blockIdx.x, tid = threadIdx.x;
    __shared__ float red1[4], red2[4];
    const float* lg = ws + WS_LOGIT + (size_t)b * NLOG;
    float mx = -1e30f;
    for (int i = tid; i < NLOG; i += 256) mx = fmaxf(mx, lg[i]);
    int lane = tid & 63, wv = tid >> 6;
    for (int off = 32; off > 0; off >>= 1) mx = fmaxf(mx, __shfl_down(mx, off, 64));
    if (lane == 0) red1[wv] = mx;
    __syncthreads();
    mx = fmaxf(fmaxf(red1[0], red1[1]), fmaxf(red1[2], red1[3]));
    float sm = 0.f;
    for (int i = tid; i < NLOG; i += 256) sm += __expf(lg[i] - mx);
    for (int off = 32; off > 0; off >>= 1) sm += __shfl_down(sm, off, 64);
    if (lane == 0) red2[wv] = sm;
    __syncthreads();
    float inv = 1.f / (red2[0] + red2[1] + red2[2] + red2[3]);
    for (int i = tid; i < NLOG; i += 256) {
        float p = __expf(lg[i] - mx) * inv;
        if (i < V) out[b * V + i] = p;
        else ws[WS_PCOPY + b * TENC + (i - V)] = p;
    }
}

// ---------------- K9: one-hot scatter-add ----------------------------------
__global__ void k_scatter(const int* __restrict__ u_in, const int* __restrict__ m_in,
                          const float* __restrict__ ws, float* __restrict__ out) {
    int b = blockIdx.x, t = threadIdx.x;
    float p = ws[WS_PCOPY + b * TENC + t];
    int idx = (t < TU) ? u_in[b * TU + t] : m_in[b * TM + (t - TU)];
    atomicAdd(&out[(size_t)b * V + idx], p);
}

// ---------------- K10: dense pv_z_prob accumulation ------------------------
__global__ __launch_bounds__(256) void k_pv(const float* __restrict__ pvp,
                                            const float* __restrict__ ws,
                                            float* __restrict__ out) {
    int b = blockIdx.y;
    int v = blockIdx.x * 256 + threadIdx.x;
    __shared__ float p[TZ];
    if (threadIdx.x < TZ) p[threadIdx.x] = ws[WS_PCOPY + b * TENC + TU + TM + threadIdx.x];
    __syncthreads();
    if (v >= V) return;
    float acc = 0.f;
#pragma unroll 4
    for (int t = 0; t < TZ; ++t) acc += p[t] * pvp[((size_t)b * TZ + t) * V + v];
    out[(size_t)b * V + v] += acc;
}

extern "C" void kernel_launch(void* const* d_in, const int* in_sizes, int n_in,
                              void* d_out, int out_size, void* d_ws, size_t ws_size,
                              hipStream_t stream) {
    const int*   u_input   = (const int*)d_in[0];
    const float* u_h       = (const float*)d_in[2];
    const int*   m_input   = (const int*)d_in[3];
    const float* m_h       = (const float*)d_in[5];
    const float* pv_prob   = (const float*)d_in[6];
    const float* pz_h      = (const float*)d_in[7];
    const float* emb       = (const float*)d_in[9];
    const float* last_h    = (const float*)d_in[10];
    const float* W_attn    = (const float*)d_in[11];
    const float* b_attn    = (const float*)d_in[12];
    const float* v_attn    = (const float*)d_in[13];
    const float* W_ih      = (const float*)d_in[14];
    const float* W_hh      = (const float*)d_in[15];
    const float* b_ih      = (const float*)d_in[16];
    const float* b_hh      = (const float*)d_in[17];
    const float* W_gen     = (const float*)d_in[18];
    const float* b_gen     = (const float*)d_in[19];
    const float* W_cpu     = (const float*)d_in[20];
    const float* b_cpu     = (const float*)d_in[21];
    const float* W_cpm     = (const float*)d_in[22];
    const float* b_cpm     = (const float*)d_in[23];
    const float* W_cppz    = (const float*)d_in[24];
    const float* b_cppz    = (const float*)d_in[25];
    float* ws  = (float*)d_ws;
    unsigned short* bf = (unsigned short*)(ws + WS_F_TOTAL);
    float* out = (float*)d_out;

    hipLaunchKernelGGL(k_cvt_w, dim3((CVT_TOTAL + 255) / 256), dim3(256), 0, stream,
                       W_attn, W_cpu, W_cpm, W_cppz, W_gen, bf);
    hipLaunchKernelGGL(k_q_mfma, dim3(4), dim3(256), 0, stream, last_h, bf, b_attn, ws);
    hipLaunchKernelGGL(k_attn_mfma, dim3(B * 18), dim3(256), 0, stream,
                       u_h, m_h, pz_h, bf, v_attn, ws);
    hipLaunchKernelGGL(k_softmax_ctx, dim3(B, 2), dim3(256), 0, stream, u_h, m_h, pz_h, ws);
    hipLaunchKernelGGL(k_gru_mm, dim3(6, 8), dim3(256), 0, stream,
                       emb, last_h, W_ih, W_hh, b_ih, b_hh, ws);
    hipLaunchKernelGGL(k_gru_combine, dim3(64), dim3(256), 0, stream, emb, last_h, ws, out);
    hipLaunchKernelGGL(k_copy_mfma, dim3(B * 18), dim3(256), 0, stream,
                       u_h, m_h, pz_h, bf, b_cpu, b_cpm, b_cppz, ws);
    hipLaunchKernelGGL(k_score_g_mfma, dim3((V + 127) / 128), dim3(256), 0, stream,
                       bf, b_gen, ws);
    hipLaunchKernelGGL(k_softmax_out, dim3(B), dim3(256), 0, stream, ws, out);
    hipLaunchKernelGGL(k_scatter, dim3(B), dim3(256), 0, stream, u_input, m_input, ws, out);
    hipLaunchKernelGGL(k_pv, dim3(40, B), dim3(256), 0, stream, pv_prob, ws, out);
}